// Round 15
// baseline (288.543 us; speedup 1.0000x reference)
//
#include <hip/hip_runtime.h>
#include <hip/hip_bf16.h>

#define CC 192

typedef __attribute__((ext_vector_type(8))) short bf16x8;
typedef __attribute__((ext_vector_type(4))) float f32x4;

__device__ __forceinline__ unsigned short f2bf(float f) {
    unsigned int u = __float_as_uint(f);
    u = (u + 0x7fffu + ((u >> 16) & 1u)) >> 16;
    return (unsigned short)u;
}

__device__ __forceinline__ float bf2f(unsigned short u) {
    return __uint_as_float(((unsigned int)u) << 16);
}

__device__ __forceinline__ f32x4 mfma16(bf16x8 a, bf16x8 b, f32x4 c) {
    return __builtin_amdgcn_mfma_f32_16x16x32_bf16(a, b, c, 0, 0, 0);
}

// Merged prep: 4 weight transposes (f32 [K][N] -> bf16 [N][K]) + 4-class masked bias table.
// Bias table is premultiplied by 1/ln2 so softmax uses native exp2 (no per-score mul).
__global__ void k_prep(const float* __restrict__ qkv_w, const float* __restrict__ proj_w,
                       const float* __restrict__ w1, const float* __restrict__ w2,
                       const float* __restrict__ relTab,
                       unsigned short* __restrict__ qkvT, unsigned short* __restrict__ projT,
                       unsigned short* __restrict__ w1T, unsigned short* __restrict__ w2T,
                       unsigned short* __restrict__ biasT4) {
    int idx = blockIdx.x * blockDim.x + threadIdx.x;
    if (idx < 110592) { int n = idx / 192, k = idx % 192; qkvT[idx] = f2bf(qkv_w[k * 576 + n]); return; }
    idx -= 110592;
    if (idx < 36864)  { int n = idx / 192, k = idx % 192; projT[idx] = f2bf(proj_w[k * 192 + n]); return; }
    idx -= 36864;
    if (idx < 73728)  { int n = idx / 192, k = idx % 192; w1T[idx] = f2bf(w1[k * 384 + n]); return; }
    idx -= 73728;
    if (idx < 73728)  { int n = idx / 384, k = idx % 384; w2T[idx] = f2bf(w2[k * 192 + n]); return; }
    idx -= 73728;
    if (idx < 98304) {   // [cls][h][i][j]: cls = (edgeH?2:0)+(edgeW?1:0); mask pre-added; x 1/ln2
        const int cls = idx / 24576, rem = idx % 24576;
        const int h = rem >> 12, i = (rem >> 6) & 63, j = rem & 63;
        const int yi = i >> 3, xi = i & 7, yj = j >> 3, xj = j & 7;
        const int rel = (yi - yj + 7) * 15 + (xi - xj + 7);
        float v = relTab[rel * 6 + h];
        const int bH = cls >> 1, bW = cls & 1;
        const int idi = (bH ? (yi >= 4 ? 2 : 1) : 0) * 3 + (bW ? (xi >= 4 ? 2 : 1) : 0);
        const int idj = (bH ? (yj >= 4 ? 2 : 1) : 0) * 3 + (bW ? (xj >= 4 ? 2 : 1) : 0);
        if (idi != idj) v -= 100.f;   // exp2(-144+O(1)) flushes to 0: exact mask semantics
        biasT4[idx] = f2bf(v * 1.4426950408889634f);
    }
}

// FUSED Swin block: one window per block (2048 blocks), 12 waves (768 threads).
// R14-proven structure (VGPR 68, no spill, 279 us). LDS regions by phase lifetime:
//   rA [0,24K):   A (swz [64][192]) -> VT (swz [6][32][64]) -> AO -> A2
//   rQ [24K,48K): Q (swz [6][64][32]) -> P low half -> h-bf16 (swz [64][192])
//   rK [48K,72K): K (swz [6][64][32]) -> P high half -> G-half (swz [64][192], MLP two-pass)
// h kept ONLY in LDS (bf16); `out` written exactly once. Softmax/GELU on native exp2.
__global__ __launch_bounds__(768, 3) void k_fused(
    const float* __restrict__ x,
    const float* __restrict__ n1g, const float* __restrict__ n1b,
    const unsigned short* __restrict__ qkvT, const float* __restrict__ qkv_b,
    const unsigned short* __restrict__ projT, const float* __restrict__ proj_b,
    const unsigned short* __restrict__ biasT4,
    const float* __restrict__ n2g, const float* __restrict__ n2b,
    const unsigned short* __restrict__ w1T, const float* __restrict__ b1,
    const unsigned short* __restrict__ w2T, const float* __restrict__ b2,
    float* __restrict__ out)
{
    __shared__ __align__(16) char smem[73728];
    __shared__ int sOpos[64];
    char* const rA = smem;
    char* const rQ = smem + 24576;
    char* const rK = smem + 49152;

    const int tid = threadIdx.x;
    const int wid = blockIdx.x;
    const int b = wid >> 6;
    const int win = wid & 63;
    const int wh = win >> 3, ww = win & 7;
    const int lane = tid & 63;
    const int wave = tid >> 6;
    const int lhi = lane >> 4, llo = lane & 15;

    // ---------- Phase 1: LN1 + shifted window gather (512 threads, 8/token) ----------
    if (tid < 512) {
        const int tok = tid >> 3;
        const int ch0 = (tid & 7) * 24;
        const int yi = tok >> 3, xi = tok & 7;
        const int oy = (wh * 8 + yi + 4) & 63;
        const int ox = (ww * 8 + xi + 4) & 63;
        const int base = ((b * 64 + oy) * 64 + ox) * CC;
        if ((tid & 7) == 0) sOpos[tok] = base;
        float v[24];
        float s = 0.f, ss = 0.f;
        #pragma unroll
        for (int i = 0; i < 6; ++i) {
            const float4 f = *(const float4*)(x + base + ch0 + i * 4);
            v[i*4+0]=f.x; v[i*4+1]=f.y; v[i*4+2]=f.z; v[i*4+3]=f.w;
            s  += f.x + f.y + f.z + f.w;
            ss += f.x*f.x + f.y*f.y + f.z*f.z + f.w*f.w;
        }
        s  += __shfl_xor(s, 1);  s  += __shfl_xor(s, 2);  s  += __shfl_xor(s, 4);
        ss += __shfl_xor(ss, 1); ss += __shfl_xor(ss, 2); ss += __shfl_xor(ss, 4);
        const float mean = s * (1.f / 192.f);
        const float rstd = rsqrtf(ss * (1.f / 192.f) - mean * mean + 1e-5f);
        char* aBase = rA + tok * 384;
        const int sw = (tok & 7) << 4;
        #pragma unroll
        for (int i = 0; i < 12; ++i) {
            const int c = ch0 + i * 2;
            const float a0 = (v[i*2+0] - mean) * rstd * n1g[c]   + n1b[c];
            const float a1 = (v[i*2+1] - mean) * rstd * n1g[c+1] + n1b[c+1];
            *(unsigned int*)(aBase + ((c * 2) ^ sw)) =
                (unsigned int)f2bf(a0) | ((unsigned int)f2bf(a1) << 16);
        }
    }
    __syncthreads();   // bar1: A ready

    // ---------- Phase 2: QKV GEMM, wave w -> cols [48w, 48w+48) ----------
    {
        const int cbase = wave * 48;
        f32x4 acc[4][3] = {};
        #pragma unroll
        for (int ks = 0; ks < 6; ++ks) {
            bf16x8 af[4];
            const int kbyte = ks * 64 + lhi * 16;
            #pragma unroll
            for (int m = 0; m < 4; ++m) {
                const int row = m * 16 + llo;
                af[m] = *(const bf16x8*)(rA + row * 384 + (kbyte ^ ((row & 7) << 4)));
            }
            #pragma unroll
            for (int n = 0; n < 3; ++n) {
                const int col = cbase + n * 16 + llo;
                const bf16x8 bfr = *(const bf16x8*)(qkvT + col * 192 + ks * 32 + lhi * 8);
                #pragma unroll
                for (int m = 0; m < 4; ++m) acc[m][n] = mfma16(af[m], bfr, acc[m][n]);
            }
        }
        __syncthreads();   // bar2: A fully consumed; rA region free for VT
        // epilogue: +bias, scatter to Q/K/VT LDS (SCALE*1/ln2 folded into Q for exp2 softmax)
        #pragma unroll
        for (int n = 0; n < 3; ++n) {
            const int c0 = cbase + n * 16;
            const int which = c0 / 192;
            const int rem = c0 - which * 192;
            const int h = rem >> 5;
            const int d = (rem & 31) + llo;
            const float bia = qkv_b[c0 + llo];
            #pragma unroll
            for (int m = 0; m < 4; ++m) {
                #pragma unroll
                for (int r = 0; r < 4; ++r) {
                    const int row = m * 16 + lhi * 4 + r;
                    if (which == 0)
                        *(unsigned short*)(rQ + h * 4096 + row * 64 + ((2 * d) ^ ((row & 3) << 4)))
                            = f2bf((acc[m][n][r] + bia) * 0.2550510257216822f);
                    else if (which == 1)
                        *(unsigned short*)(rK + h * 4096 + row * 64 + ((2 * d) ^ ((row & 3) << 4)))
                            = f2bf(acc[m][n][r] + bia);
                    else
                        *(unsigned short*)(rA + h * 4096 + d * 128 + ((2 * row) ^ ((d & 7) << 4)))
                            = f2bf(acc[m][n][r] + bia);
                }
            }
        }
    }
    __syncthreads();   // bar3: Q/K/VT visible

    // ---------- Phase 3: attention (head = wave>>1, row-half = wave&1) ----------
    const int h = wave >> 1;
    const int mh = wave & 1;
    f32x4 pacc[2][2] = {};
    float rinv[2][4];
    {
        bf16x8 qf[2], kf[4];
        #pragma unroll
        for (int m = 0; m < 2; ++m) {
            const int t = (mh * 2 + m) * 16 + llo;
            qf[m] = *(const bf16x8*)(rQ + h * 4096 + t * 64 + ((lhi * 16) ^ ((t & 3) << 4)));
        }
        #pragma unroll
        for (int n = 0; n < 4; ++n) {
            const int t = n * 16 + llo;
            kf[n] = *(const bf16x8*)(rK + h * 4096 + t * 64 + ((lhi * 16) ^ ((t & 3) << 4)));
        }
        __syncthreads();   // bar4: Q/K in registers everywhere; rQ+rK free for P

        f32x4 sacc[2][4] = {};
        #pragma unroll
        for (int m = 0; m < 2; ++m)
            #pragma unroll
            for (int n = 0; n < 4; ++n)
                sacc[m][n] = mfma16(qf[m], kf[n], sacc[m][n]);

        // 4-class premasked, pre-1/ln2 bias table: softmax on native exp2, no-max
        const int cls = ((wh == 7) ? 2 : 0) + ((ww == 7) ? 1 : 0);
        const unsigned short* bT = biasT4 + cls * 24576 + h * 4096;
        #pragma unroll
        for (int m = 0; m < 2; ++m) {
            #pragma unroll
            for (int r = 0; r < 4; ++r) {
                const int i = (mh * 2 + m) * 16 + lhi * 4 + r;
                float sum = 0.f;
                unsigned short pb[4];
                #pragma unroll
                for (int n = 0; n < 4; ++n) {
                    const int j = n * 16 + llo;
                    const float e = exp2f(sacc[m][n][r] + bf2f(bT[i * 64 + j]));
                    sum += e;
                    pb[n] = f2bf(e);
                }
                sum += __shfl_xor(sum, 1);
                sum += __shfl_xor(sum, 2);
                sum += __shfl_xor(sum, 4);
                sum += __shfl_xor(sum, 8);
                rinv[m][r] = 1.f / sum;
                #pragma unroll
                for (int n = 0; n < 4; ++n) {
                    const int j = n * 16 + llo;
                    *(unsigned short*)(rQ + h * 8192 + i * 128 + ((2 * j) ^ ((i & 7) << 4))) = pb[n];
                }
            }
        }
        // P is wave-private (own 32 rows) -> no barrier before PV.
        #pragma unroll
        for (int ks = 0; ks < 2; ++ks) {
            bf16x8 pf[2];
            #pragma unroll
            for (int m = 0; m < 2; ++m) {
                const int t = (mh * 2 + m) * 16 + llo;
                pf[m] = *(const bf16x8*)(rQ + h * 8192 + t * 128 + ((ks * 64 + lhi * 16) ^ ((t & 7) << 4)));
            }
            #pragma unroll
            for (int n = 0; n < 2; ++n) {
                const int d = n * 16 + llo;
                const bf16x8 vf = *(const bf16x8*)(rA + h * 4096 + d * 128 + ((ks * 64 + lhi * 16) ^ ((d & 7) << 4)));
                #pragma unroll
                for (int m = 0; m < 2; ++m) pacc[m][n] = mfma16(pf[m], vf, pacc[m][n]);
            }
        }
    }
    __syncthreads();   // bar5: all VT/P reads done; rA free for AO
    {
        #pragma unroll
        for (int m = 0; m < 2; ++m) {
            #pragma unroll
            for (int n = 0; n < 2; ++n) {
                const int c = h * 32 + n * 16 + llo;
                #pragma unroll
                for (int r = 0; r < 4; ++r) {
                    const int i = (mh * 2 + m) * 16 + lhi * 4 + r;
                    *(unsigned short*)(rA + i * 384 + ((c * 2) ^ ((i & 7) << 4)))
                        = f2bf(pacc[m][n][r] * rinv[m][r]);
                }
            }
        }
    }
    __syncthreads();   // bar6: AO ready

    // ---------- Phase 4: proj GEMM + residual -> h (bf16) kept in LDS at rQ ----------
    {
        const int cbase = wave * 16;
        f32x4 acc[4] = {};
        #pragma unroll
        for (int ks = 0; ks < 6; ++ks) {
            bf16x8 af[4];
            const int kbyte = ks * 64 + lhi * 16;
            #pragma unroll
            for (int m = 0; m < 4; ++m) {
                const int row = m * 16 + llo;
                af[m] = *(const bf16x8*)(rA + row * 384 + (kbyte ^ ((row & 7) << 4)));
            }
            const int col = cbase + llo;
            const bf16x8 bfr = *(const bf16x8*)(projT + col * 192 + ks * 32 + lhi * 8);
            #pragma unroll
            for (int m = 0; m < 4; ++m) acc[m] = mfma16(af[m], bfr, acc[m]);
        }
        const int c = cbase + llo;
        const float pb = proj_b[c];
        #pragma unroll
        for (int m = 0; m < 4; ++m) {
            #pragma unroll
            for (int r = 0; r < 4; ++r) {
                const int i = m * 16 + lhi * 4 + r;
                const float hv = x[sOpos[i] + c] + acc[m][r] + pb;
                *(unsigned short*)(rQ + i * 384 + ((2 * c) ^ ((i & 7) << 4))) = f2bf(hv);
            }
        }
    }
    __syncthreads();   // bar7: h-bf16 visible in rQ

    // ---------- Phase 5: LN2 from LDS h -> A2 at rA ----------
    if (tid < 512) {
        const int tok = tid >> 3;
        const int ch0 = (tid & 7) * 24;
        const int sw = (tok & 7) << 4;
        float v[24]; float s = 0.f, ss = 0.f;
        #pragma unroll
        for (int i = 0; i < 12; ++i) {
            const int c = ch0 + i * 2;
            const unsigned uu = *(const unsigned*)(rQ + tok * 384 + ((2 * c) ^ sw));
            const float a0 = bf2f((unsigned short)uu);
            const float a1 = bf2f((unsigned short)(uu >> 16));
            v[2*i] = a0; v[2*i+1] = a1;
            s += a0 + a1;
            ss += a0 * a0 + a1 * a1;
        }
        s  += __shfl_xor(s, 1);  s  += __shfl_xor(s, 2);  s  += __shfl_xor(s, 4);
        ss += __shfl_xor(ss, 1); ss += __shfl_xor(ss, 2); ss += __shfl_xor(ss, 4);
        const float mean = s * (1.f / 192.f);
        const float rstd = rsqrtf(ss * (1.f / 192.f) - mean * mean + 1e-5f);
        char* aBase = rA + tok * 384;
        #pragma unroll
        for (int i = 0; i < 12; ++i) {
            const int c = ch0 + i * 2;
            const float a0 = (v[i*2]   - mean) * rstd * n2g[c]   + n2b[c];
            const float a1 = (v[i*2+1] - mean) * rstd * n2g[c+1] + n2b[c+1];
            *(unsigned int*)(aBase + ((c * 2) ^ sw)) =
                (unsigned int)f2bf(a0) | ((unsigned int)f2bf(a1) << 16);
        }
    }
    __syncthreads();   // bar8: A2 ready; rK free for G-half

    // ---------- Phase 6: MLP in two hidden halves; G-half [64][192] at rK ----------
    f32x4 accM[4] = {};
    #pragma unroll
    for (int hh = 0; hh < 2; ++hh) {
        // GEMM1 half: cols [hh*192 + 16w, +16), exp2-GELU -> G-half
        {
            f32x4 a1[4] = {};
            #pragma unroll
            for (int ks = 0; ks < 6; ++ks) {
                bf16x8 af[4];
                const int kbyte = ks * 64 + lhi * 16;
                #pragma unroll
                for (int m = 0; m < 4; ++m) {
                    const int row = m * 16 + llo;
                    af[m] = *(const bf16x8*)(rA + row * 384 + (kbyte ^ ((row & 7) << 4)));
                }
                const bf16x8 bfr = *(const bf16x8*)(w1T + (hh * 192 + wave * 16 + llo) * 192 + ks * 32 + lhi * 8);
                #pragma unroll
                for (int m = 0; m < 4; ++m) a1[m] = mfma16(af[m], bfr, a1[m]);
            }
            const int cl = wave * 16 + llo;
            const float bb = b1[hh * 192 + cl];
            #pragma unroll
            for (int m = 0; m < 4; ++m) {
                #pragma unroll
                for (int r = 0; r < 4; ++r) {
                    const int i = m * 16 + lhi * 4 + r;
                    const float u = a1[m][r] + bb;
                    // gelu_tanh == u / (1 + e^{-2k(u+0.044715u^3)}); 2k/ln2 folded for exp2
                    const float xx = 2.3022211096534824f * (u + 0.044715f * u * u * u);
                    const float g = u / (1.f + exp2f(-xx));
                    *(unsigned short*)(rK + i * 384 + ((2 * cl) ^ ((i & 7) << 4))) = f2bf(g);
                }
            }
        }
        __syncthreads();   // G-half ready
        // GEMM2 partial: K = [hh*192,+192), wave -> out cols [16w,+16)
        {
            #pragma unroll
            for (int ks = 0; ks < 6; ++ks) {
                bf16x8 af[4];
                const int kbyte = ks * 64 + lhi * 16;
                #pragma unroll
                for (int m = 0; m < 4; ++m) {
                    const int row = m * 16 + llo;
                    af[m] = *(const bf16x8*)(rK + row * 384 + (kbyte ^ ((row & 7) << 4)));
                }
                const bf16x8 bfr = *(const bf16x8*)(w2T + (wave * 16 + llo) * 384 + hh * 192 + ks * 32 + lhi * 8);
                #pragma unroll
                for (int m = 0; m < 4; ++m) accM[m] = mfma16(af[m], bfr, accM[m]);
            }
        }
        if (hh == 0) __syncthreads();   // G-half0 consumed; final barrier dropped (no LDS use after)
    }
    // ---------- final: out = h + mlp (single global write) ----------
    {
        const int c = wave * 16 + llo;
        const float bb = b2[c];
        #pragma unroll
        for (int m = 0; m < 4; ++m) {
            #pragma unroll
            for (int r = 0; r < 4; ++r) {
                const int i = m * 16 + lhi * 4 + r;
                const float hv = bf2f(*(const unsigned short*)(rQ + i * 384 + ((2 * c) ^ ((i & 7) << 4))));
                out[sOpos[i] + c] = hv + accM[m][r] + bb;
            }
        }
    }
}

extern "C" void kernel_launch(void* const* d_in, const int* in_sizes, int n_in,
                              void* d_out, int out_size, void* d_ws, size_t ws_size,
                              hipStream_t stream)
{
    const float* x      = (const float*)d_in[0];
    const float* n1g    = (const float*)d_in[1];
    const float* n1b    = (const float*)d_in[2];
    const float* qkv_w  = (const float*)d_in[3];
    const float* qkv_b  = (const float*)d_in[4];
    const float* proj_w = (const float*)d_in[5];
    const float* proj_b = (const float*)d_in[6];
    const float* relTab = (const float*)d_in[7];
    const float* n2g    = (const float*)d_in[8];
    const float* n2b    = (const float*)d_in[9];
    const float* w1     = (const float*)d_in[10];
    const float* b1     = (const float*)d_in[11];
    const float* w2     = (const float*)d_in[12];
    const float* b2     = (const float*)d_in[13];
    float* out = (float*)d_out;

    char* ws = (char*)d_ws;
    unsigned short* qkvT   = (unsigned short*)(ws);            // [576][192] bf16
    unsigned short* projT  = (unsigned short*)(ws + 221184);   // [192][192] bf16
    unsigned short* w1T    = (unsigned short*)(ws + 294912);   // [384][192] bf16
    unsigned short* w2T    = (unsigned short*)(ws + 442368);   // [192][384] bf16
    unsigned short* biasT4 = (unsigned short*)(ws + 589824);   // [4][6][64][64] bf16 (masked, /ln2)

    k_prep<<<1536, 256, 0, stream>>>(qkv_w, proj_w, w1, w2, relTab, qkvT, projT, w1T, w2T, biasT4);
    k_fused<<<2048, 768, 0, stream>>>(x, n1g, n1b, qkvT, qkv_b, projT, proj_b, biasT4,
                                      n2g, n2b, w1T, b1, w2T, b2, out);
}

// Round 16
// 277.150 us; speedup vs baseline: 1.0411x; 1.0411x over previous
//
#include <hip/hip_runtime.h>
#include <hip/hip_bf16.h>

#define CC 192

typedef __attribute__((ext_vector_type(8))) short bf16x8;
typedef __attribute__((ext_vector_type(4))) float f32x4;

__device__ __forceinline__ unsigned short f2bf(float f) {
    unsigned int u = __float_as_uint(f);
    u = (u + 0x7fffu + ((u >> 16) & 1u)) >> 16;
    return (unsigned short)u;
}

__device__ __forceinline__ float bf2f(unsigned short u) {
    return __uint_as_float(((unsigned int)u) << 16);
}

// 2^x via the native v_exp_f32 (single VALU op). exp2f() goes through ocml (slow path);
// __expf() emits mul+exp. This is the minimal form.
__device__ __forceinline__ float fast_exp2(float x) {
#if __has_builtin(__builtin_amdgcn_exp2f)
    return __builtin_amdgcn_exp2f(x);
#else
    return __expf(0.69314718055994531f * x);
#endif
}

__device__ __forceinline__ f32x4 mfma16(bf16x8 a, bf16x8 b, f32x4 c) {
    return __builtin_amdgcn_mfma_f32_16x16x32_bf16(a, b, c, 0, 0, 0);
}

// Merged prep: 4 weight transposes (f32 [K][N] -> bf16 [N][K]) + 4-class masked bias table.
// Bias table is premultiplied by 1/ln2 so softmax uses native exp2 (no per-score mul).
__global__ void k_prep(const float* __restrict__ qkv_w, const float* __restrict__ proj_w,
                       const float* __restrict__ w1, const float* __restrict__ w2,
                       const float* __restrict__ relTab,
                       unsigned short* __restrict__ qkvT, unsigned short* __restrict__ projT,
                       unsigned short* __restrict__ w1T, unsigned short* __restrict__ w2T,
                       unsigned short* __restrict__ biasT4) {
    int idx = blockIdx.x * blockDim.x + threadIdx.x;
    if (idx < 110592) { int n = idx / 192, k = idx % 192; qkvT[idx] = f2bf(qkv_w[k * 576 + n]); return; }
    idx -= 110592;
    if (idx < 36864)  { int n = idx / 192, k = idx % 192; projT[idx] = f2bf(proj_w[k * 192 + n]); return; }
    idx -= 36864;
    if (idx < 73728)  { int n = idx / 192, k = idx % 192; w1T[idx] = f2bf(w1[k * 384 + n]); return; }
    idx -= 73728;
    if (idx < 73728)  { int n = idx / 384, k = idx % 384; w2T[idx] = f2bf(w2[k * 192 + n]); return; }
    idx -= 73728;
    if (idx < 98304) {   // [cls][h][i][j]: cls = (edgeH?2:0)+(edgeW?1:0); mask pre-added; x 1/ln2
        const int cls = idx / 24576, rem = idx % 24576;
        const int h = rem >> 12, i = (rem >> 6) & 63, j = rem & 63;
        const int yi = i >> 3, xi = i & 7, yj = j >> 3, xj = j & 7;
        const int rel = (yi - yj + 7) * 15 + (xi - xj + 7);
        float v = relTab[rel * 6 + h];
        const int bH = cls >> 1, bW = cls & 1;
        const int idi = (bH ? (yi >= 4 ? 2 : 1) : 0) * 3 + (bW ? (xi >= 4 ? 2 : 1) : 0);
        const int idj = (bH ? (yj >= 4 ? 2 : 1) : 0) * 3 + (bW ? (xj >= 4 ? 2 : 1) : 0);
        if (idi != idj) v -= 100.f;   // exp2(-144+O(1)) flushes to 0: exact mask semantics
        biasT4[idx] = f2bf(v * 1.4426950408889634f);
    }
}

// FUSED Swin block: one window per block (2048 blocks), 12 waves (768 threads).
// R14-proven structure (VGPR 68, no spill). LDS regions by phase lifetime:
//   rA [0,24K):   A (swz [64][192]) -> VT (swz [6][32][64]) -> AO -> A2
//   rQ [24K,48K): Q (swz [6][64][32]) -> P low half -> h-bf16 (swz [64][192])
//   rK [48K,72K): K (swz [6][64][32]) -> P high half -> G-half (swz [64][192], MLP two-pass)
// h kept ONLY in LDS (bf16); `out` written exactly once. Softmax/GELU on native v_exp_f32.
__global__ __launch_bounds__(768, 3) void k_fused(
    const float* __restrict__ x,
    const float* __restrict__ n1g, const float* __restrict__ n1b,
    const unsigned short* __restrict__ qkvT, const float* __restrict__ qkv_b,
    const unsigned short* __restrict__ projT, const float* __restrict__ proj_b,
    const unsigned short* __restrict__ biasT4,
    const float* __restrict__ n2g, const float* __restrict__ n2b,
    const unsigned short* __restrict__ w1T, const float* __restrict__ b1,
    const unsigned short* __restrict__ w2T, const float* __restrict__ b2,
    float* __restrict__ out)
{
    __shared__ __align__(16) char smem[73728];
    __shared__ int sOpos[64];
    char* const rA = smem;
    char* const rQ = smem + 24576;
    char* const rK = smem + 49152;

    const int tid = threadIdx.x;
    const int wid = blockIdx.x;
    const int b = wid >> 6;
    const int win = wid & 63;
    const int wh = win >> 3, ww = win & 7;
    const int lane = tid & 63;
    const int wave = tid >> 6;
    const int lhi = lane >> 4, llo = lane & 15;

    // ---------- Phase 1: LN1 + shifted window gather (512 threads, 8/token) ----------
    if (tid < 512) {
        const int tok = tid >> 3;
        const int ch0 = (tid & 7) * 24;
        const int yi = tok >> 3, xi = tok & 7;
        const int oy = (wh * 8 + yi + 4) & 63;
        const int ox = (ww * 8 + xi + 4) & 63;
        const int base = ((b * 64 + oy) * 64 + ox) * CC;
        if ((tid & 7) == 0) sOpos[tok] = base;
        float v[24];
        float s = 0.f, ss = 0.f;
        #pragma unroll
        for (int i = 0; i < 6; ++i) {
            const float4 f = *(const float4*)(x + base + ch0 + i * 4);
            v[i*4+0]=f.x; v[i*4+1]=f.y; v[i*4+2]=f.z; v[i*4+3]=f.w;
            s  += f.x + f.y + f.z + f.w;
            ss += f.x*f.x + f.y*f.y + f.z*f.z + f.w*f.w;
        }
        s  += __shfl_xor(s, 1);  s  += __shfl_xor(s, 2);  s  += __shfl_xor(s, 4);
        ss += __shfl_xor(ss, 1); ss += __shfl_xor(ss, 2); ss += __shfl_xor(ss, 4);
        const float mean = s * (1.f / 192.f);
        const float rstd = rsqrtf(ss * (1.f / 192.f) - mean * mean + 1e-5f);
        char* aBase = rA + tok * 384;
        const int sw = (tok & 7) << 4;
        #pragma unroll
        for (int i = 0; i < 12; ++i) {
            const int c = ch0 + i * 2;
            const float a0 = (v[i*2+0] - mean) * rstd * n1g[c]   + n1b[c];
            const float a1 = (v[i*2+1] - mean) * rstd * n1g[c+1] + n1b[c+1];
            *(unsigned int*)(aBase + ((c * 2) ^ sw)) =
                (unsigned int)f2bf(a0) | ((unsigned int)f2bf(a1) << 16);
        }
    }
    __syncthreads();   // bar1: A ready

    // ---------- Phase 2: QKV GEMM, wave w -> cols [48w, 48w+48) ----------
    {
        const int cbase = wave * 48;
        f32x4 acc[4][3] = {};
        #pragma unroll
        for (int ks = 0; ks < 6; ++ks) {
            bf16x8 af[4];
            const int kbyte = ks * 64 + lhi * 16;
            #pragma unroll
            for (int m = 0; m < 4; ++m) {
                const int row = m * 16 + llo;
                af[m] = *(const bf16x8*)(rA + row * 384 + (kbyte ^ ((row & 7) << 4)));
            }
            #pragma unroll
            for (int n = 0; n < 3; ++n) {
                const int col = cbase + n * 16 + llo;
                const bf16x8 bfr = *(const bf16x8*)(qkvT + col * 192 + ks * 32 + lhi * 8);
                #pragma unroll
                for (int m = 0; m < 4; ++m) acc[m][n] = mfma16(af[m], bfr, acc[m][n]);
            }
        }
        __syncthreads();   // bar2: A fully consumed; rA region free for VT
        // epilogue: +bias, scatter to Q/K/VT LDS (SCALE*1/ln2 folded into Q for exp2 softmax)
        #pragma unroll
        for (int n = 0; n < 3; ++n) {
            const int c0 = cbase + n * 16;
            const int which = c0 / 192;
            const int rem = c0 - which * 192;
            const int h = rem >> 5;
            const int d = (rem & 31) + llo;
            const float bia = qkv_b[c0 + llo];
            #pragma unroll
            for (int m = 0; m < 4; ++m) {
                #pragma unroll
                for (int r = 0; r < 4; ++r) {
                    const int row = m * 16 + lhi * 4 + r;
                    if (which == 0)
                        *(unsigned short*)(rQ + h * 4096 + row * 64 + ((2 * d) ^ ((row & 3) << 4)))
                            = f2bf((acc[m][n][r] + bia) * 0.2550510257216822f);
                    else if (which == 1)
                        *(unsigned short*)(rK + h * 4096 + row * 64 + ((2 * d) ^ ((row & 3) << 4)))
                            = f2bf(acc[m][n][r] + bia);
                    else
                        *(unsigned short*)(rA + h * 4096 + d * 128 + ((2 * row) ^ ((d & 7) << 4)))
                            = f2bf(acc[m][n][r] + bia);
                }
            }
        }
    }
    __syncthreads();   // bar3: Q/K/VT visible

    // ---------- Phase 3: attention (head = wave>>1, row-half = wave&1) ----------
    const int h = wave >> 1;
    const int mh = wave & 1;
    f32x4 pacc[2][2] = {};
    float rinv[2][4];
    {
        bf16x8 qf[2], kf[4];
        #pragma unroll
        for (int m = 0; m < 2; ++m) {
            const int t = (mh * 2 + m) * 16 + llo;
            qf[m] = *(const bf16x8*)(rQ + h * 4096 + t * 64 + ((lhi * 16) ^ ((t & 3) << 4)));
        }
        #pragma unroll
        for (int n = 0; n < 4; ++n) {
            const int t = n * 16 + llo;
            kf[n] = *(const bf16x8*)(rK + h * 4096 + t * 64 + ((lhi * 16) ^ ((t & 3) << 4)));
        }
        __syncthreads();   // bar4: Q/K in registers everywhere; rQ+rK free for P

        f32x4 sacc[2][4] = {};
        #pragma unroll
        for (int m = 0; m < 2; ++m)
            #pragma unroll
            for (int n = 0; n < 4; ++n)
                sacc[m][n] = mfma16(qf[m], kf[n], sacc[m][n]);

        // 4-class premasked, pre-1/ln2 bias table: softmax on native exp2, no-max
        const int cls = ((wh == 7) ? 2 : 0) + ((ww == 7) ? 1 : 0);
        const unsigned short* bT = biasT4 + cls * 24576 + h * 4096;
        #pragma unroll
        for (int m = 0; m < 2; ++m) {
            #pragma unroll
            for (int r = 0; r < 4; ++r) {
                const int i = (mh * 2 + m) * 16 + lhi * 4 + r;
                float sum = 0.f;
                unsigned short pb[4];
                #pragma unroll
                for (int n = 0; n < 4; ++n) {
                    const int j = n * 16 + llo;
                    const float e = fast_exp2(sacc[m][n][r] + bf2f(bT[i * 64 + j]));
                    sum += e;
                    pb[n] = f2bf(e);
                }
                sum += __shfl_xor(sum, 1);
                sum += __shfl_xor(sum, 2);
                sum += __shfl_xor(sum, 4);
                sum += __shfl_xor(sum, 8);
                rinv[m][r] = 1.f / sum;
                #pragma unroll
                for (int n = 0; n < 4; ++n) {
                    const int j = n * 16 + llo;
                    *(unsigned short*)(rQ + h * 8192 + i * 128 + ((2 * j) ^ ((i & 7) << 4))) = pb[n];
                }
            }
        }
        // P is wave-private (own 32 rows) -> no barrier before PV.
        #pragma unroll
        for (int ks = 0; ks < 2; ++ks) {
            bf16x8 pf[2];
            #pragma unroll
            for (int m = 0; m < 2; ++m) {
                const int t = (mh * 2 + m) * 16 + llo;
                pf[m] = *(const bf16x8*)(rQ + h * 8192 + t * 128 + ((ks * 64 + lhi * 16) ^ ((t & 7) << 4)));
            }
            #pragma unroll
            for (int n = 0; n < 2; ++n) {
                const int d = n * 16 + llo;
                const bf16x8 vf = *(const bf16x8*)(rA + h * 4096 + d * 128 + ((ks * 64 + lhi * 16) ^ ((d & 7) << 4)));
                #pragma unroll
                for (int m = 0; m < 2; ++m) pacc[m][n] = mfma16(pf[m], vf, pacc[m][n]);
            }
        }
    }
    __syncthreads();   // bar5: all VT/P reads done; rA free for AO
    {
        #pragma unroll
        for (int m = 0; m < 2; ++m) {
            #pragma unroll
            for (int n = 0; n < 2; ++n) {
                const int c = h * 32 + n * 16 + llo;
                #pragma unroll
                for (int r = 0; r < 4; ++r) {
                    const int i = (mh * 2 + m) * 16 + lhi * 4 + r;
                    *(unsigned short*)(rA + i * 384 + ((c * 2) ^ ((i & 7) << 4)))
                        = f2bf(pacc[m][n][r] * rinv[m][r]);
                }
            }
        }
    }
    __syncthreads();   // bar6: AO ready

    // ---------- Phase 4: proj GEMM + residual -> h (bf16) kept in LDS at rQ ----------
    {
        const int cbase = wave * 16;
        f32x4 acc[4] = {};
        #pragma unroll
        for (int ks = 0; ks < 6; ++ks) {
            bf16x8 af[4];
            const int kbyte = ks * 64 + lhi * 16;
            #pragma unroll
            for (int m = 0; m < 4; ++m) {
                const int row = m * 16 + llo;
                af[m] = *(const bf16x8*)(rA + row * 384 + (kbyte ^ ((row & 7) << 4)));
            }
            const int col = cbase + llo;
            const bf16x8 bfr = *(const bf16x8*)(projT + col * 192 + ks * 32 + lhi * 8);
            #pragma unroll
            for (int m = 0; m < 4; ++m) acc[m] = mfma16(af[m], bfr, acc[m]);
        }
        const int c = cbase + llo;
        const float pb = proj_b[c];
        #pragma unroll
        for (int m = 0; m < 4; ++m) {
            #pragma unroll
            for (int r = 0; r < 4; ++r) {
                const int i = m * 16 + lhi * 4 + r;
                const float hv = x[sOpos[i] + c] + acc[m][r] + pb;
                *(unsigned short*)(rQ + i * 384 + ((2 * c) ^ ((i & 7) << 4))) = f2bf(hv);
            }
        }
    }
    __syncthreads();   // bar7: h-bf16 visible in rQ

    // ---------- Phase 5: LN2 from LDS h -> A2 at rA ----------
    if (tid < 512) {
        const int tok = tid >> 3;
        const int ch0 = (tid & 7) * 24;
        const int sw = (tok & 7) << 4;
        float v[24]; float s = 0.f, ss = 0.f;
        #pragma unroll
        for (int i = 0; i < 12; ++i) {
            const int c = ch0 + i * 2;
            const unsigned uu = *(const unsigned*)(rQ + tok * 384 + ((2 * c) ^ sw));
            const float a0 = bf2f((unsigned short)uu);
            const float a1 = bf2f((unsigned short)(uu >> 16));
            v[2*i] = a0; v[2*i+1] = a1;
            s += a0 + a1;
            ss += a0 * a0 + a1 * a1;
        }
        s  += __shfl_xor(s, 1);  s  += __shfl_xor(s, 2);  s  += __shfl_xor(s, 4);
        ss += __shfl_xor(ss, 1); ss += __shfl_xor(ss, 2); ss += __shfl_xor(ss, 4);
        const float mean = s * (1.f / 192.f);
        const float rstd = rsqrtf(ss * (1.f / 192.f) - mean * mean + 1e-5f);
        char* aBase = rA + tok * 384;
        #pragma unroll
        for (int i = 0; i < 12; ++i) {
            const int c = ch0 + i * 2;
            const float a0 = (v[i*2]   - mean) * rstd * n2g[c]   + n2b[c];
            const float a1 = (v[i*2+1] - mean) * rstd * n2g[c+1] + n2b[c+1];
            *(unsigned int*)(aBase + ((c * 2) ^ sw)) =
                (unsigned int)f2bf(a0) | ((unsigned int)f2bf(a1) << 16);
        }
    }
    __syncthreads();   // bar8: A2 ready; rK free for G-half

    // ---------- Phase 6: MLP in two hidden halves; G-half [64][192] at rK ----------
    f32x4 accM[4] = {};
    #pragma unroll
    for (int hh = 0; hh < 2; ++hh) {
        // GEMM1 half: cols [hh*192 + 16w, +16), native-exp2 GELU -> G-half
        {
            f32x4 a1[4] = {};
            #pragma unroll
            for (int ks = 0; ks < 6; ++ks) {
                bf16x8 af[4];
                const int kbyte = ks * 64 + lhi * 16;
                #pragma unroll
                for (int m = 0; m < 4; ++m) {
                    const int row = m * 16 + llo;
                    af[m] = *(const bf16x8*)(rA + row * 384 + (kbyte ^ ((row & 7) << 4)));
                }
                const bf16x8 bfr = *(const bf16x8*)(w1T + (hh * 192 + wave * 16 + llo) * 192 + ks * 32 + lhi * 8);
                #pragma unroll
                for (int m = 0; m < 4; ++m) a1[m] = mfma16(af[m], bfr, a1[m]);
            }
            const int cl = wave * 16 + llo;
            const float bb = b1[hh * 192 + cl];
            #pragma unroll
            for (int m = 0; m < 4; ++m) {
                #pragma unroll
                for (int r = 0; r < 4; ++r) {
                    const int i = m * 16 + lhi * 4 + r;
                    const float u = a1[m][r] + bb;
                    // gelu_tanh == u / (1 + 2^{-2k/ln2 (u+0.044715u^3)})
                    const float xx = 2.3022211096534824f * (u + 0.044715f * u * u * u);
                    const float g = u / (1.f + fast_exp2(-xx));
                    *(unsigned short*)(rK + i * 384 + ((2 * cl) ^ ((i & 7) << 4))) = f2bf(g);
                }
            }
        }
        __syncthreads();   // G-half ready
        // GEMM2 partial: K = [hh*192,+192), wave -> out cols [16w,+16)
        {
            #pragma unroll
            for (int ks = 0; ks < 6; ++ks) {
                bf16x8 af[4];
                const int kbyte = ks * 64 + lhi * 16;
                #pragma unroll
                for (int m = 0; m < 4; ++m) {
                    const int row = m * 16 + llo;
                    af[m] = *(const bf16x8*)(rK + row * 384 + (kbyte ^ ((row & 7) << 4)));
                }
                const bf16x8 bfr = *(const bf16x8*)(w2T + (wave * 16 + llo) * 384 + hh * 192 + ks * 32 + lhi * 8);
                #pragma unroll
                for (int m = 0; m < 4; ++m) accM[m] = mfma16(af[m], bfr, accM[m]);
            }
        }
        if (hh == 0) __syncthreads();   // G-half0 consumed; final barrier dropped (no LDS use after)
    }
    // ---------- final: out = h + mlp (single global write) ----------
    {
        const int c = wave * 16 + llo;
        const float bb = b2[c];
        #pragma unroll
        for (int m = 0; m < 4; ++m) {
            #pragma unroll
            for (int r = 0; r < 4; ++r) {
                const int i = m * 16 + lhi * 4 + r;
                const float hv = bf2f(*(const unsigned short*)(rQ + i * 384 + ((2 * c) ^ ((i & 7) << 4))));
                out[sOpos[i] + c] = hv + accM[m][r] + bb;
            }
        }
    }
}

extern "C" void kernel_launch(void* const* d_in, const int* in_sizes, int n_in,
                              void* d_out, int out_size, void* d_ws, size_t ws_size,
                              hipStream_t stream)
{
    const float* x      = (const float*)d_in[0];
    const float* n1g    = (const float*)d_in[1];
    const float* n1b    = (const float*)d_in[2];
    const float* qkv_w  = (const float*)d_in[3];
    const float* qkv_b  = (const float*)d_in[4];
    const float* proj_w = (const float*)d_in[5];
    const float* proj_b = (const float*)d_in[6];
    const float* relTab = (const float*)d_in[7];
    const float* n2g    = (const float*)d_in[8];
    const float* n2b    = (const float*)d_in[9];
    const float* w1     = (const float*)d_in[10];
    const float* b1     = (const float*)d_in[11];
    const float* w2     = (const float*)d_in[12];
    const float* b2     = (const float*)d_in[13];
    float* out = (float*)d_out;

    char* ws = (char*)d_ws;
    unsigned short* qkvT   = (unsigned short*)(ws);            // [576][192] bf16
    unsigned short* projT  = (unsigned short*)(ws + 221184);   // [192][192] bf16
    unsigned short* w1T    = (unsigned short*)(ws + 294912);   // [384][192] bf16
    unsigned short* w2T    = (unsigned short*)(ws + 442368);   // [192][384] bf16
    unsigned short* biasT4 = (unsigned short*)(ws + 589824);   // [4][6][64][64] bf16 (masked, /ln2)

    k_prep<<<1536, 256, 0, stream>>>(qkv_w, proj_w, w1, w2, relTab, qkvT, projT, w1T, w2T, biasT4);
    k_fused<<<2048, 768, 0, stream>>>(x, n1g, n1b, qkvT, qkv_b, projT, proj_b, biasT4,
                                      n2g, n2b, w1T, b1, w2T, b2, out);
}